// Round 11
// baseline (232.827 us; speedup 1.0000x reference)
//
#include <hip/hip_runtime.h>
#include <stdint.h>

#define MD 8192
#define ND 8192
#define KD 2048
#define KTH 15099494  // int(8192*2048*0.9)

#define NCOPY 16   // privatized LDS histogram copies
#define HSTR 257   // copy stride in words; 257 % 32 == 1 -> distinct banks per copy
#define NPART 8    // global histogram partials

typedef int v4i __attribute__((ext_vector_type(4)));

__device__ __forceinline__ void gload_lds16(const void* g, void* l) {
  __builtin_amdgcn_global_load_lds(
      (const __attribute__((address_space(1))) uint32_t*)g,
      (__attribute__((address_space(3))) uint32_t*)l, 16, 0, 0);
}

// ---------------- absmax: both tensors, ONE global atomic per block ----------------
__global__ void absmax2_kernel(const float* __restrict__ x1, const float* __restrict__ x2,
                               unsigned int* sbits) {
  __shared__ float wred[4];
  const float4* p = (const float4*)(blockIdx.y ? x2 : x1);
  const int n4 = MD * KD / 4;
  int tid = blockIdx.x * blockDim.x + threadIdx.x;
  int stride = gridDim.x * blockDim.x;
  float m = 0.f;
  for (int i = tid; i < n4; i += stride) {
    float4 v = p[i];
    m = fmaxf(m, fmaxf(fmaxf(fabsf(v.x), fabsf(v.y)), fmaxf(fabsf(v.z), fabsf(v.w))));
  }
  #pragma unroll
  for (int off = 32; off; off >>= 1) m = fmaxf(m, __shfl_down(m, off, 64));
  if ((threadIdx.x & 63) == 0) wred[threadIdx.x >> 6] = m;
  __syncthreads();
  if (threadIdx.x == 0) {
    float bm = fmaxf(fmaxf(wred[0], wred[1]), fmaxf(wred[2], wred[3]));
    atomicMax(&sbits[blockIdx.y], __float_as_uint(bm));
  }
}

// ---------------- quantize x1 (row-major keep) + privatized histogram ----------------
__global__ void quant_hist_kernel(const float* __restrict__ x, int8_t* __restrict__ q,
                                  int n4, const unsigned int* sbits, unsigned int* hist) {
  __shared__ unsigned int h[NCOPY * HSTR];
  for (int i = threadIdx.x; i < NCOPY * HSTR; i += blockDim.x) h[i] = 0;
  __syncthreads();
  unsigned int* hc = h + (threadIdx.x & (NCOPY - 1)) * HSTR;
  float s = __uint_as_float(*sbits);
  int tid = blockIdx.x * blockDim.x + threadIdx.x;
  int stride = gridDim.x * blockDim.x;
  const float4* p = (const float4*)x;
  uint32_t* qo = (uint32_t*)q;
  for (int i = tid; i < n4; i += stride) {
    float4 v = p[i];
    int q0 = (int)rintf(v.x / s * 127.0f);   // keep (x/s)*127 order: matches np bit-exactly
    int q1 = (int)rintf(v.y / s * 127.0f);
    int q2 = (int)rintf(v.z / s * 127.0f);
    int q3 = (int)rintf(v.w / s * 127.0f);
    atomicAdd(&hc[q0 + 127], 1u);
    atomicAdd(&hc[q1 + 127], 1u);
    atomicAdd(&hc[q2 + 127], 1u);
    atomicAdd(&hc[q3 + 127], 1u);
    uint32_t packed = (uint32_t)(uint8_t)(int8_t)q0 |
                      ((uint32_t)(uint8_t)(int8_t)q1 << 8) |
                      ((uint32_t)(uint8_t)(int8_t)q2 << 16) |
                      ((uint32_t)(uint8_t)(int8_t)q3 << 24);
    qo[i] = packed;
  }
  __syncthreads();
  {
    int b = threadIdx.x;
    unsigned int sum = 0;
    #pragma unroll
    for (int c = 0; c < NCOPY; ++c) sum += h[c * HSTR + b];
    if (sum) atomicAdd(&hist[(blockIdx.x & (NPART - 1)) * 256 + b], sum);
  }
}

// ---------------- quantize x2 transposed ([K][N] -> q2t[N][K]) + privatized histogram ----
#define TSTR 17
__global__ void transq_kernel(const float* __restrict__ x, int8_t* __restrict__ qt,
                              const unsigned int* sbits, unsigned int* hist) {
  __shared__ unsigned int tile2[64 * TSTR];
  __shared__ unsigned int h[NCOPY * HSTR];
  for (int i = threadIdx.x; i < NCOPY * HSTR; i += blockDim.x) h[i] = 0;
  __syncthreads();
  unsigned int* hc = h + (threadIdx.x & (NCOPY - 1)) * HSTR;
  float s = __uint_as_float(*sbits);
  int n0 = blockIdx.x * 64, k0 = blockIdx.y * 64;
  int t = threadIdx.x;
  int nq = t & 15, kq = t >> 4;
  unsigned int pk[4] = {0, 0, 0, 0};
  #pragma unroll
  for (int j = 0; j < 4; ++j) {
    float4 v = *(const float4*)(x + (size_t)(k0 + kq * 4 + j) * ND + n0 + nq * 4);
    int q0 = (int)rintf(v.x / s * 127.0f);
    int q1 = (int)rintf(v.y / s * 127.0f);
    int q2 = (int)rintf(v.z / s * 127.0f);
    int q3 = (int)rintf(v.w / s * 127.0f);
    atomicAdd(&hc[q0 + 127], 1u);
    atomicAdd(&hc[q1 + 127], 1u);
    atomicAdd(&hc[q2 + 127], 1u);
    atomicAdd(&hc[q3 + 127], 1u);
    pk[0] |= ((unsigned int)(uint8_t)(int8_t)q0) << (8 * j);
    pk[1] |= ((unsigned int)(uint8_t)(int8_t)q1) << (8 * j);
    pk[2] |= ((unsigned int)(uint8_t)(int8_t)q2) << (8 * j);
    pk[3] |= ((unsigned int)(uint8_t)(int8_t)q3) << (8 * j);
  }
  #pragma unroll
  for (int i = 0; i < 4; ++i) tile2[(nq * 4 + i) * TSTR + kq] = pk[i];
  __syncthreads();
  {
    int n = t >> 2, c = t & 3;
    uint4 val;
    val.x = tile2[n * TSTR + c * 4 + 0];
    val.y = tile2[n * TSTR + c * 4 + 1];
    val.z = tile2[n * TSTR + c * 4 + 2];
    val.w = tile2[n * TSTR + c * 4 + 3];
    *(uint4*)(qt + (size_t)(n0 + n) * KD + k0 + c * 16) = val;
  }
  __syncthreads();
  {
    int b = threadIdx.x;
    unsigned int sum = 0;
    #pragma unroll
    for (int c = 0; c < NCOPY; ++c) sum += h[c * HSTR + b];
    if (sum) atomicAdd(&hist[((blockIdx.x + blockIdx.y) & (NPART - 1)) * 256 + b], sum);
  }
}

// ---------------- kth-value: sum partials, prefix scan, pick crossing ----------------
__global__ void finalize_kernel(const unsigned int* __restrict__ hist1,
                                const unsigned int* __restrict__ hist2,
                                float* __restrict__ out_k) {
  __shared__ unsigned int c[256];
  __shared__ int result;
  int t = threadIdx.x;
  const unsigned int* h = (blockIdx.x == 0) ? hist1 : hist2;
  unsigned int sum = 0;
  #pragma unroll
  for (int p = 0; p < NPART; ++p) sum += h[p * 256 + t];
  c[t] = sum;
  if (t == 0) result = 127;
  __syncthreads();
  #pragma unroll
  for (int off = 1; off < 256; off <<= 1) {
    unsigned int add = (t >= off) ? c[t - off] : 0u;
    __syncthreads();
    c[t] += add;
    __syncthreads();
  }
  unsigned int prev = (t == 0) ? 0u : c[t - 1];
  if (c[t] >= (unsigned int)KTH && prev < (unsigned int)KTH) result = t - 127;
  __syncthreads();
  if (t == 0) out_k[blockIdx.x] = (float)result;
}

// ---------------- i8 GEMM: intensity-corrected m201 analog ----------------
// 256x256 tile, 512 thr (8 waves 2Mx4N), wave tile 128x64. BK=128 (i8 1B x
// K128 == bf16 2B x K64: per K-tile per wave 64 MFMA / 24 ds_read / 64KB
// staged == m201's exact economics). LDS: 2 dbuf x 32KB x {A,B} = 128KB.
// K-tile = 4 phases (kh x m-half), each {frag reads pre-BAR, stage, BAR,
// lgkm0, 16 MFMA, BAR} (round-7's proven skeleton). Staging halves of tile
// k+1 issue at phases 0/1 (2-3 phases ~1300-2000cy cover > 900cy HBM);
// vmcnt(0)+BAR once per tile at phase 3 confirms tile k+1.
// Swizzle: BK=128 rows = 8 chunks, chunk ^= row&7 both sides (round-3's
// 0-conflict involution). Race audit: reads(k) pre-BAR target region k&1
// confirmed at k-1 ph3; STAGE(k+1) targets region (k+1)&1=(k-1)&1, last read
// in tile k-1 whose reads completed before its closing barriers.
#define NKT 16  // KD/128
__global__ __launch_bounds__(512, 2) void gemm_i8_kernel(
    const int8_t* __restrict__ qa, const int8_t* __restrict__ qb,
    float* __restrict__ out, const unsigned int* __restrict__ sbits) {
  extern __shared__ __align__(16) int8_t L[];  // A: [0,64K) 2 bufs; B: [64K,128K)

  int bid = blockIdx.x;
  int xcd = bid & 7;
  int local = bid >> 3;               // 0..127
  int brow = xcd * 4 + (local & 3);   // 0..31
  int bcol = local >> 2;              // 0..31

  int t = threadIdx.x;
  int lane = t & 63;
  int w = t >> 6;
  int wr = (w >> 2) * 128;   // 0 | 128
  int wc = (w & 3) * 64;     // 0,64,128,192

  v4i acc[8][4] = {};

  const int8_t* ga = qa + (size_t)brow * 256 * KD;
  const int8_t* gb = qb + (size_t)bcol * 256 * KD;

  int srow = t >> 3;   // 0..63 (row within a 64-row staging pass)
  int sc = t & 7;      // chunk slot (8 x 16B per 128B row)

  auto STAGE_HALF = [&](int k, int half) {  // 4 gloads: 2 A + 2 B
    int reg = (k & 1) * 32768;
    int kcol = k * 128;
    #pragma unroll
    for (int j = 0; j < 2; ++j) {
      int row = half * 128 + j * 64 + srow;
      int gc = sc ^ (row & 7);   // pre-swizzled source, linear LDS dest
      gload_lds16(ga + (size_t)row * KD + kcol + gc * 16, L + reg + row * 128 + sc * 16);
      gload_lds16(gb + (size_t)row * KD + kcol + gc * 16, L + 65536 + reg + row * 128 + sc * 16);
    }
  };

  auto KTILE = [&](int k, bool stage) {
    const int8_t* LA = L + (k & 1) * 32768;
    const int8_t* LB = L + 65536 + (k & 1) * 32768;
    v4i aF[4], bF[4];
    #pragma unroll
    for (int kh = 0; kh < 2; ++kh) {
      // ---- phase (kh, mh=0): bF(kh) + aF(rows 0-127) reads, stage half kh ----
      #pragma unroll
      for (int n = 0; n < 4; ++n) {
        int row = wc + n * 16 + (lane & 15);
        int c = (kh * 4 + (lane >> 4)) ^ (row & 7);
        bF[n] = *(const v4i*)(LB + row * 128 + c * 16);
      }
      #pragma unroll
      for (int m = 0; m < 4; ++m) {
        int row = wr + m * 16 + (lane & 15);
        int c = (kh * 4 + (lane >> 4)) ^ (row & 7);
        aF[m] = *(const v4i*)(LA + row * 128 + c * 16);
      }
      if (stage && kh == 0) STAGE_HALF(k + 1, 0);
      __builtin_amdgcn_sched_barrier(0);
      __builtin_amdgcn_s_barrier();
      asm volatile("s_waitcnt lgkmcnt(0)" ::: "memory");
      __builtin_amdgcn_sched_barrier(0);
      __builtin_amdgcn_s_setprio(1);
      #pragma unroll
      for (int m = 0; m < 4; ++m)
        #pragma unroll
        for (int n = 0; n < 4; ++n)
          acc[m][n] = __builtin_amdgcn_mfma_i32_16x16x64_i8(aF[m], bF[n], acc[m][n], 0, 0, 0);
      __builtin_amdgcn_s_setprio(0);
      __builtin_amdgcn_sched_barrier(0);
      __builtin_amdgcn_s_barrier();
      __builtin_amdgcn_sched_barrier(0);
      // ---- phase (kh, mh=1): aF(rows 128-255), bF reused in regs ----
      #pragma unroll
      for (int m = 0; m < 4; ++m) {
        int row = wr + 64 + m * 16 + (lane & 15);
        int c = (kh * 4 + (lane >> 4)) ^ (row & 7);
        aF[m] = *(const v4i*)(LA + row * 128 + c * 16);
      }
      if (stage && kh == 0) STAGE_HALF(k + 1, 1);
      if (kh == 1) {  // close the K-tile: confirm tile k+1 fully staged
        if (stage) asm volatile("s_waitcnt vmcnt(0)" ::: "memory");
      }
      __builtin_amdgcn_sched_barrier(0);
      __builtin_amdgcn_s_barrier();
      asm volatile("s_waitcnt lgkmcnt(0)" ::: "memory");
      __builtin_amdgcn_sched_barrier(0);
      __builtin_amdgcn_s_setprio(1);
      #pragma unroll
      for (int m = 0; m < 4; ++m)
        #pragma unroll
        for (int n = 0; n < 4; ++n)
          acc[4 + m][n] = __builtin_amdgcn_mfma_i32_16x16x64_i8(aF[m], bF[n], acc[4 + m][n], 0, 0, 0);
      __builtin_amdgcn_s_setprio(0);
      __builtin_amdgcn_sched_barrier(0);
      __builtin_amdgcn_s_barrier();
      __builtin_amdgcn_sched_barrier(0);
    }
  };

  // prologue: stage tile 0, drain, barrier
  STAGE_HALF(0, 0);
  STAGE_HALF(0, 1);
  asm volatile("s_waitcnt vmcnt(0)" ::: "memory");
  __builtin_amdgcn_s_barrier();

  for (int k = 0; k < NKT - 1; ++k) KTILE(k, true);
  KTILE(NKT - 1, false);

  float s1 = __uint_as_float(sbits[0]);
  float s2 = __uint_as_float(sbits[1]);
  float scale = s1 * s2 / (127.0f * 127.0f);
  int orow = brow * 256 + wr + ((lane >> 4) * 4);
  int ocol = bcol * 256 + wc + (lane & 15);
  #pragma unroll
  for (int m = 0; m < 8; ++m)
    #pragma unroll
    for (int n = 0; n < 4; ++n)
      #pragma unroll
      for (int r = 0; r < 4; ++r)
        out[(size_t)(orow + m * 16 + r) * ND + (ocol + n * 16)] = (float)acc[m][n][r] * scale;
}

extern "C" void kernel_launch(void* const* d_in, const int* in_sizes, int n_in,
                              void* d_out, int out_size, void* d_ws, size_t ws_size,
                              hipStream_t stream) {
  const float* x1 = (const float*)d_in[0];
  const float* x2 = (const float*)d_in[1];
  float* out = (float*)d_out;
  uint8_t* ws = (uint8_t*)d_ws;

  unsigned int* sbits = (unsigned int*)ws;
  unsigned int* hist1 = (unsigned int*)(ws + 256);
  unsigned int* hist2 = (unsigned int*)(ws + 256 + 8192);
  int8_t* q1  = (int8_t*)(ws + 32768);
  int8_t* q2t = q1 + (size_t)MD * KD;

  const int n4_1 = MD * KD / 4;
  const int n4_2 = KD * ND / 4;

  hipFuncSetAttribute((const void*)gemm_i8_kernel,
                      hipFuncAttributeMaxDynamicSharedMemorySize, 131072);

  hipMemsetAsync(ws, 0, 32768, stream);
  absmax2_kernel<<<dim3(512, 2), 256, 0, stream>>>(x1, x2, sbits);
  quant_hist_kernel<<<1024, 256, 0, stream>>>(x1, q1, n4_1, sbits + 0, hist1);
  transq_kernel<<<dim3(ND / 64, KD / 64), 256, 0, stream>>>(x2, q2t, sbits + 1, hist2);
  finalize_kernel<<<2, 256, 0, stream>>>(hist1, hist2, out + (size_t)MD * ND);
  gemm_i8_kernel<<<1024, 512, 131072, stream>>>(q1, q2t, out, sbits);
}

// Round 12
// 228.602 us; speedup vs baseline: 1.0185x; 1.0185x over previous
//
#include <hip/hip_runtime.h>
#include <stdint.h>

#define MD 8192
#define ND 8192
#define KD 2048
#define KTH 15099494  // int(8192*2048*0.9)

#define NCOPY 16   // privatized LDS histogram copies
#define HSTR 257   // copy stride in words; 257 % 32 == 1 -> distinct banks per copy
#define NPART 8    // global histogram partials

typedef int v4i __attribute__((ext_vector_type(4)));

__device__ __forceinline__ void gload_lds16(const void* g, void* l) {
  __builtin_amdgcn_global_load_lds(
      (const __attribute__((address_space(1))) uint32_t*)g,
      (__attribute__((address_space(3))) uint32_t*)l, 16, 0, 0);
}

// ---------------- absmax: both tensors, ONE global atomic per block ----------------
__global__ void absmax2_kernel(const float* __restrict__ x1, const float* __restrict__ x2,
                               unsigned int* sbits) {
  __shared__ float wred[4];
  const float4* p = (const float4*)(blockIdx.y ? x2 : x1);
  const int n4 = MD * KD / 4;
  int tid = blockIdx.x * blockDim.x + threadIdx.x;
  int stride = gridDim.x * blockDim.x;
  float m = 0.f;
  for (int i = tid; i < n4; i += stride) {
    float4 v = p[i];
    m = fmaxf(m, fmaxf(fmaxf(fabsf(v.x), fabsf(v.y)), fmaxf(fabsf(v.z), fabsf(v.w))));
  }
  #pragma unroll
  for (int off = 32; off; off >>= 1) m = fmaxf(m, __shfl_down(m, off, 64));
  if ((threadIdx.x & 63) == 0) wred[threadIdx.x >> 6] = m;
  __syncthreads();
  if (threadIdx.x == 0) {
    float bm = fmaxf(fmaxf(wred[0], wred[1]), fmaxf(wred[2], wred[3]));
    atomicMax(&sbits[blockIdx.y], __float_as_uint(bm));
  }
}

// ---------------- quantize x1 (row-major keep) + privatized histogram ----------------
__global__ void quant_hist_kernel(const float* __restrict__ x, int8_t* __restrict__ q,
                                  int n4, const unsigned int* sbits, unsigned int* hist) {
  __shared__ unsigned int h[NCOPY * HSTR];
  for (int i = threadIdx.x; i < NCOPY * HSTR; i += blockDim.x) h[i] = 0;
  __syncthreads();
  unsigned int* hc = h + (threadIdx.x & (NCOPY - 1)) * HSTR;
  float s = __uint_as_float(*sbits);
  int tid = blockIdx.x * blockDim.x + threadIdx.x;
  int stride = gridDim.x * blockDim.x;
  const float4* p = (const float4*)x;
  uint32_t* qo = (uint32_t*)q;
  for (int i = tid; i < n4; i += stride) {
    float4 v = p[i];
    int q0 = (int)rintf(v.x / s * 127.0f);   // keep (x/s)*127 order: matches np bit-exactly
    int q1 = (int)rintf(v.y / s * 127.0f);
    int q2 = (int)rintf(v.z / s * 127.0f);
    int q3 = (int)rintf(v.w / s * 127.0f);
    atomicAdd(&hc[q0 + 127], 1u);
    atomicAdd(&hc[q1 + 127], 1u);
    atomicAdd(&hc[q2 + 127], 1u);
    atomicAdd(&hc[q3 + 127], 1u);
    uint32_t packed = (uint32_t)(uint8_t)(int8_t)q0 |
                      ((uint32_t)(uint8_t)(int8_t)q1 << 8) |
                      ((uint32_t)(uint8_t)(int8_t)q2 << 16) |
                      ((uint32_t)(uint8_t)(int8_t)q3 << 24);
    qo[i] = packed;
  }
  __syncthreads();
  {
    int b = threadIdx.x;
    unsigned int sum = 0;
    #pragma unroll
    for (int c = 0; c < NCOPY; ++c) sum += h[c * HSTR + b];
    if (sum) atomicAdd(&hist[(blockIdx.x & (NPART - 1)) * 256 + b], sum);
  }
}

// ---------------- quantize x2 -> B' FRAGMENT-MAJOR + privatized histogram ----------------
// B'[ng][kg][lane][16B]: ng = ncol/16, kg = k/64, lane = (ncol&15) + ((k>>4)&3)*16.
// A wave's GEMM bF read becomes ONE coalesced global_load_dwordx4 (1024B block).
#define TSTR 17
__global__ void transq_kernel(const float* __restrict__ x, int8_t* __restrict__ qt,
                              const unsigned int* sbits, unsigned int* hist) {
  __shared__ unsigned int tile2[64 * TSTR];
  __shared__ unsigned int h[NCOPY * HSTR];
  for (int i = threadIdx.x; i < NCOPY * HSTR; i += blockDim.x) h[i] = 0;
  __syncthreads();
  unsigned int* hc = h + (threadIdx.x & (NCOPY - 1)) * HSTR;
  float s = __uint_as_float(*sbits);
  int n0 = blockIdx.x * 64, k0 = blockIdx.y * 64;
  int t = threadIdx.x;
  int nq = t & 15, kq = t >> 4;
  unsigned int pk[4] = {0, 0, 0, 0};
  #pragma unroll
  for (int j = 0; j < 4; ++j) {
    float4 v = *(const float4*)(x + (size_t)(k0 + kq * 4 + j) * ND + n0 + nq * 4);
    int q0 = (int)rintf(v.x / s * 127.0f);
    int q1 = (int)rintf(v.y / s * 127.0f);
    int q2 = (int)rintf(v.z / s * 127.0f);
    int q3 = (int)rintf(v.w / s * 127.0f);
    atomicAdd(&hc[q0 + 127], 1u);
    atomicAdd(&hc[q1 + 127], 1u);
    atomicAdd(&hc[q2 + 127], 1u);
    atomicAdd(&hc[q3 + 127], 1u);
    pk[0] |= ((unsigned int)(uint8_t)(int8_t)q0) << (8 * j);
    pk[1] |= ((unsigned int)(uint8_t)(int8_t)q1) << (8 * j);
    pk[2] |= ((unsigned int)(uint8_t)(int8_t)q2) << (8 * j);
    pk[3] |= ((unsigned int)(uint8_t)(int8_t)q3) << (8 * j);
  }
  #pragma unroll
  for (int i = 0; i < 4; ++i) tile2[(nq * 4 + i) * TSTR + kq] = pk[i];
  __syncthreads();
  {
    int nl = t >> 2, kc = t & 3;          // local ncol, 16B k-chunk
    uint4 val;
    val.x = tile2[nl * TSTR + kc * 4 + 0];
    val.y = tile2[nl * TSTR + kc * 4 + 1];
    val.z = tile2[nl * TSTR + kc * 4 + 2];
    val.w = tile2[nl * TSTR + kc * 4 + 3];
    int n = n0 + nl;
    int ng = n >> 4;
    int kg = k0 >> 6;                      // kc*16 < 64 -> same k-group
    int lanep = (n & 15) + kc * 16;
    *(uint4*)(qt + ((size_t)ng * (KD >> 6) + kg) * 1024 + lanep * 16) = val;
  }
  __syncthreads();
  {
    int b = threadIdx.x;
    unsigned int sum = 0;
    #pragma unroll
    for (int c = 0; c < NCOPY; ++c) sum += h[c * HSTR + b];
    if (sum) atomicAdd(&hist[((blockIdx.x + blockIdx.y) & (NPART - 1)) * 256 + b], sum);
  }
}

// ---------------- kth-value: sum partials, prefix scan, pick crossing ----------------
__global__ void finalize_kernel(const unsigned int* __restrict__ hist1,
                                const unsigned int* __restrict__ hist2,
                                float* __restrict__ out_k) {
  __shared__ unsigned int c[256];
  __shared__ int result;
  int t = threadIdx.x;
  const unsigned int* h = (blockIdx.x == 0) ? hist1 : hist2;
  unsigned int sum = 0;
  #pragma unroll
  for (int p = 0; p < NPART; ++p) sum += h[p * 256 + t];
  c[t] = sum;
  if (t == 0) result = 127;
  __syncthreads();
  #pragma unroll
  for (int off = 1; off < 256; off <<= 1) {
    unsigned int add = (t >= off) ? c[t - off] : 0u;
    __syncthreads();
    c[t] += add;
    __syncthreads();
  }
  unsigned int prev = (t == 0) ? 0u : c[t - 1];
  if (c[t] >= (unsigned int)KTH && prev < (unsigned int)KTH) result = t - 127;
  __syncthreads();
  if (t == 0) out_k[blockIdx.x] = (float)result;
}

// ---------------- i8 GEMM: round-3 structure, B direct-from-global fragments --------
// 128x128 tile, BK=128, 4 waves 2x2 (64x64 each). A: LDS single-buffer 16KB,
// R3's proven swizzled gload_lds + ds_read (0 conflicts). B: NO LDS — each bF
// is one coalesced global_load_dwordx4 from fragment-major B' (L2-resident
// 1MB/XCD stripe). LDS traffic/block-K-tile halves (96->48KB, 375cy vs MFMA
// 653cy); launch_bounds(256,4) -> 4 blocks/CU (16 waves) of TLP hide L2 lat.
__global__ __launch_bounds__(256, 4) void gemm_i8_kernel(
    const int8_t* __restrict__ qa, const int8_t* __restrict__ qb,
    float* __restrict__ out, const unsigned int* __restrict__ sbits) {
  __shared__ __align__(16) int8_t Asm[128 * 128];

  // XCD supergroup (bijective, 4096 = 8*8*64): 8 consecutive blocks share bcol
  int bid = blockIdx.x;
  int xcd = bid & 7;
  int local = bid >> 3;               // 0..511
  int brow = xcd * 8 + (local & 7);   // 0..63
  int bcol = local >> 3;              // 0..63

  int t = threadIdx.x;
  int lane = t & 63;
  int w = t >> 6;
  int wr = (w >> 1) * 64, wc = (w & 1) * 64;

  v4i acc[4][4] = {};

  const int8_t* ga = qa + (size_t)brow * 128 * KD;
  const int8_t* gb = qb + ((size_t)(bcol * 8 + (wc >> 4)) * (KD >> 6)) * 1024;

  int srow = t >> 3;     // 0..31 (row within 32-row staging slab)
  int schunk = t & 7;    // swizzled 16B-chunk slot in LDS row

  for (int kt = 0; kt < KD / 128; ++kt) {
    int kbase = kt * 128;
    #pragma unroll
    for (int i = 0; i < 4; ++i) {
      int row = i * 32 + srow;
      int gchunk = schunk ^ (row & 7);  // pre-swizzled global source
      gload_lds16(ga + (size_t)row * KD + kbase + gchunk * 16, Asm + i * 4096 + t * 16);
    }
    __syncthreads();
    #pragma unroll
    for (int kh = 0; kh < 2; ++kh) {
      v4i aF[4], bF[4];
      #pragma unroll
      for (int n = 0; n < 4; ++n)  // one coalesced 1024B fragment block each
        bF[n] = *(const v4i*)(gb + ((size_t)n * (KD >> 6) + kt * 2 + kh) * 1024 + lane * 16);
      #pragma unroll
      for (int m = 0; m < 4; ++m) {
        int row = wr + m * 16 + (lane & 15);
        int chunk = (kh * 4 + (lane >> 4)) ^ (row & 7);
        aF[m] = *(const v4i*)(Asm + row * 128 + chunk * 16);
      }
      #pragma unroll
      for (int m = 0; m < 4; ++m)
        #pragma unroll
        for (int n = 0; n < 4; ++n)
          acc[m][n] = __builtin_amdgcn_mfma_i32_16x16x64_i8(aF[m], bF[n], acc[m][n], 0, 0, 0);
    }
    __syncthreads();
  }

  float s1 = __uint_as_float(sbits[0]);
  float s2 = __uint_as_float(sbits[1]);
  float scale = s1 * s2 / (127.0f * 127.0f);
  int orow = brow * 128 + wr + ((lane >> 4) * 4);
  int ocol = bcol * 128 + wc + (lane & 15);
  #pragma unroll
  for (int m = 0; m < 4; ++m)
    #pragma unroll
    for (int n = 0; n < 4; ++n)
      #pragma unroll
      for (int r = 0; r < 4; ++r)
        out[(size_t)(orow + m * 16 + r) * ND + (ocol + n * 16)] = (float)acc[m][n][r] * scale;
}

extern "C" void kernel_launch(void* const* d_in, const int* in_sizes, int n_in,
                              void* d_out, int out_size, void* d_ws, size_t ws_size,
                              hipStream_t stream) {
  const float* x1 = (const float*)d_in[0];
  const float* x2 = (const float*)d_in[1];
  float* out = (float*)d_out;
  uint8_t* ws = (uint8_t*)d_ws;

  unsigned int* sbits = (unsigned int*)ws;
  unsigned int* hist1 = (unsigned int*)(ws + 256);
  unsigned int* hist2 = (unsigned int*)(ws + 256 + 8192);
  int8_t* q1  = (int8_t*)(ws + 32768);
  int8_t* q2t = q1 + (size_t)MD * KD;   // B' fragment-major, 16 MB

  const int n4_1 = MD * KD / 4;
  const int n4_2 = KD * ND / 4;

  hipMemsetAsync(ws, 0, 32768, stream);
  absmax2_kernel<<<dim3(512, 2), 256, 0, stream>>>(x1, x2, sbits);
  quant_hist_kernel<<<1024, 256, 0, stream>>>(x1, q1, n4_1, sbits + 0, hist1);
  transq_kernel<<<dim3(ND / 64, KD / 64), 256, 0, stream>>>(x2, q2t, sbits + 1, hist2);
  finalize_kernel<<<2, 256, 0, stream>>>(hist1, hist2, out + (size_t)MD * ND);
  gemm_i8_kernel<<<4096, 256, 0, stream>>>(q1, q2t, out, sbits);
}